// Round 1
// baseline (317.475 us; speedup 1.0000x reference)
//
#include <hip/hip_runtime.h>
#include <math.h>

#define B_TOT 512
#define S_LEN 256
#define D_IN  64
#define HDIM  128

// ---- fast scalar ops (raw HW instructions; ~1-2 ulp, threshold is 1.5e-2) ----
__device__ __forceinline__ float rcp_f(float x) { return __builtin_amdgcn_rcpf(x); }
__device__ __forceinline__ float rsq_f(float x) { return __builtin_amdgcn_rsqf(x); }
__device__ __forceinline__ float sig_f(float x) { return rcp_f(1.0f + __expf(-x)); }
__device__ __forceinline__ float tanh_f(float x) { return 1.0f - 2.0f * rcp_f(1.0f + __expf(2.0f * x)); }

// ---- DPP butterfly add (VALU pipe) ----
template<int CTRL>
__device__ __forceinline__ float dpp_add(float v) {
    int t = __builtin_amdgcn_update_dpp(0, __float_as_int(v), CTRL, 0xF, 0xF, true);
    return v + __int_as_float(t);
}

// Full 64-lane butterfly sum; result broadcast to ALL lanes (stays in VGPR).
// xor1,2,4,8 via DPP; xor16 via ds_swizzle (32-lane domain); xor32 via ds_bpermute.
__device__ __forceinline__ float allsum64(float v, int idx32) {
    v = dpp_add<0xB1>(v);    // xor 1
    v = dpp_add<0x4E>(v);    // xor 2
    v = dpp_add<0x141>(v);   // xor 4 (row_half_mirror, valid on 4-uniform data)
    v = dpp_add<0x140>(v);   // xor 8 (row_mirror, valid on 8-uniform data)
    int s = __builtin_amdgcn_ds_swizzle(__float_as_int(v), 0x401F); // lane ^= 16
    v += __int_as_float(s);
    int t = __builtin_amdgcn_ds_bpermute(idx32, __float_as_int(v)); // lane ^= 32
    v += __int_as_float(t);
    return v;
}

// 2 waves per batch element. Wave w owns hidden units [w*64, w*64+64) (unit = w*64+lane,
// h/c live in that wave's registers) and x features [w*32, w*32+32) (lanes 0..31).
// Per step the waves exchange only the four 64-lane partial sums y_q through LDS.
__global__ void __launch_bounds__(128, 1) qlstm_kernel(
    const float* __restrict__ x,    // (B,S,D)
    const float* __restrict__ Win,  // (192,4)
    const float* __restrict__ bin,  // (4)
    const float* __restrict__ Wout, // (4,128)
    const float* __restrict__ bout, // (128)
    const float* __restrict__ wf,   // (1,3,4)
    const float* __restrict__ wi,
    const float* __restrict__ wu,
    const float* __restrict__ wo,
    float* __restrict__ out)        // outs (B,S,128) ++ hT (B,128) ++ cT (B,128)
{
    const int b   = blockIdx.x;        // batch element
    const int tid = threadIdx.x;       // 0..127
    const int w   = tid >> 6;          // wave id 0/1
    const int l   = tid & 63;          // lane 0..63
    const int u   = (w << 6) + l;      // this lane's hidden unit
    const int idx32 = (l ^ 32) << 2;   // bpermute byte index for lane^32

    __shared__ float4 xch[2][2];       // [wave][parity] partial-sum exchange slots

    // ---- per-lane constant weights ----
    const float4* W4 = reinterpret_cast<const float4*>(Win);
    const float4 wh = W4[u];           // W_in row for this lane's h unit
    float4 wx;
    if (l < 32) wx = W4[128 + (w << 5) + l];   // W_in row for x feature w*32+l
    else        wx = make_float4(0.f, 0.f, 0.f, 0.f);
    // b_in folded pre-reduction: each of the 128 lanes adds b/128; 2-wave sum gives b.
    const float4 bn4 = *reinterpret_cast<const float4*>(bin);
    const float bn0 = bn4.x * 0.0078125f, bn1 = bn4.y * 0.0078125f,
                bn2 = bn4.z * 0.0078125f, bn3 = bn4.w * 0.0078125f;

    float Wo[4];
#pragma unroll
    for (int q = 0; q < 4; ++q) Wo[q] = Wout[q * HDIM + u];
    const float bo_u = bout[u];

    // ---- per-(gate,qubit) measurement coefficients u = (-sin b, cos b sin a, cos b cos a)
    float U[4][4][3];
    {
        const float* wg[4] = {wf, wi, wu, wo};
#pragma unroll
        for (int g = 0; g < 4; ++g) {
#pragma unroll
            for (int q = 0; q < 4; ++q) {
                float a  = wg[g][q];
                float be = wg[g][4 + q];
                float sa = sinf(a),  ca = cosf(a);
                float sb = sinf(be), cb = cosf(be);
                U[g][q][0] = -sb;
                U[g][q][1] = cb * sa;
                U[g][q][2] = cb * ca;
            }
        }
    }

    // ---- recurrent state: ONE unit per lane ----
    float h = 0.f, c = 0.f;

    const float* xb = x + (size_t)b * (S_LEN * D_IN) + ((w << 5) + (l & 31));
    float* ob = out + (size_t)b * (S_LEN * HDIM) + u;

    // register prefetch of x, one 4-step group ahead (raw barriers below do NOT
    // drain vmcnt, so these loads stay in flight across step barriers)
    float xcur[4], xnxt[4];
#pragma unroll
    for (int j = 0; j < 4; ++j) {
        xcur[j] = xb[(size_t)j * D_IN];
        xnxt[j] = xb[(size_t)(4 + j) * D_IN];
    }

    for (int t4 = 0; t4 < S_LEN / 4; ++t4) {
#pragma unroll
        for (int j = 0; j < 4; ++j) {
            const int par = j & 1;
            const float xv = xcur[j];

            // partial pre-activations for this wave's 96 reduction inputs
            float p0 = fmaf(h, wh.x, fmaf(xv, wx.x, bn0));
            float p1 = fmaf(h, wh.y, fmaf(xv, wx.y, bn1));
            float p2 = fmaf(h, wh.z, fmaf(xv, wx.z, bn2));
            float p3 = fmaf(h, wh.w, fmaf(xv, wx.w, bn3));
            float y0 = allsum64(p0, idx32);
            float y1 = allsum64(p1, idx32);
            float y2 = allsum64(p2, idx32);
            float y3 = allsum64(p3, idx32);

            // ---- cross-wave exchange of the 4 partial sums (16 B via LDS) ----
            if (l == 0) xch[w][par] = make_float4(y0, y1, y2, y3);
            asm volatile("s_waitcnt lgkmcnt(0)" ::: "memory");
            __builtin_amdgcn_s_barrier();
            asm volatile("" ::: "memory");
            const float4 pv = xch[w ^ 1][par];
            y0 += pv.x; y1 += pv.y; y2 += pv.z; y3 += pv.w;

            const float ys[4] = {y0, y1, y2, y3};

            // Bloch vectors (arctan's cancel analytically)
            float nx[4], ny[4], nz[4];
#pragma unroll
            for (int q = 0; q < 4; ++q) {
                float y   = ys[q];
                float y2s = y * y;
                float r1  = rsq_f(fmaf(y, y, 1.0f));
                float r2  = rsq_f(fmaf(y2s, y2s, 1.0f));
                float xx  = r1 * r2;
                nx[q] = xx;
                ny[q] = y2s * xx;
                nz[q] = -y * r1;
            }

            // Pauli-string products (CNOT-ring conjugation)
            float nz01 = nz[0] * nz[1];
            float nz23 = nz[2] * nz[3];
            float TX[4], TY[4], TZ[4];
            TX[0] = nx[0] * nx[1];
            TX[1] = nx[1] * nx[2];
            TX[2] = nx[2] * nx[3];
            TX[3] = TX[0] * nx[3];
            TZ[0] = nz[1] * nz23;
            TZ[1] = nz01;
            TZ[2] = nz01 * nz[2];
            TZ[3] = nz01 * nz23;
            TY[0] = (nx[0] * ny[1]) * nz23;
            TY[1] = (nz[0] * ny[1]) * nx[2];
            TY[2] = (nz01 * ny[2]) * nx[3];
            TY[3] = -(ny[0] * ny[1]) * (nz[2] * ny[3]);

            // gate pre-activations for this lane's single unit
            float pre[4];
#pragma unroll
            for (int g = 0; g < 4; ++g) {
                float s = bo_u;
#pragma unroll
                for (int q = 0; q < 4; ++q) {
                    float z = fmaf(U[g][q][0], TX[q],
                              fmaf(U[g][q][1], TY[q],
                                   U[g][q][2] * TZ[q]));
                    s = fmaf(z, Wo[q], s);
                }
                pre[g] = s;
            }

            float fg = sig_f(pre[0]);
            float ig = sig_f(pre[1]);
            float gg = tanh_f(pre[2]);
            float og = sig_f(pre[3]);
            c = fmaf(fg, c, ig * gg);
            h = og * tanh_f(c);

            // store this step's output (fire-and-forget; drained only at kernel end)
            ob[(size_t)(t4 * 4 + j) * HDIM] = h;
        }
        // rotate prefetched x, prefetch next group (clamped)
#pragma unroll
        for (int j = 0; j < 4; ++j) xcur[j] = xnxt[j];
        const int tb = (t4 + 2) * 4;
#pragma unroll
        for (int j = 0; j < 4; ++j) {
            int tn = tb + j;
            if (tn > S_LEN - 1) tn = S_LEN - 1;
            xnxt[j] = xb[(size_t)tn * D_IN];
        }
    }

    // final h, c
    float* hT = out + (size_t)B_TOT * S_LEN * HDIM;
    float* cT = hT + (size_t)B_TOT * HDIM;
    hT[(size_t)b * HDIM + u] = h;
    cT[(size_t)b * HDIM + u] = c;
}

extern "C" void kernel_launch(void* const* d_in, const int* in_sizes, int n_in,
                              void* d_out, int out_size, void* d_ws, size_t ws_size,
                              hipStream_t stream) {
    qlstm_kernel<<<dim3(B_TOT), dim3(128), 0, stream>>>(
        (const float*)d_in[0],  // x
        (const float*)d_in[1],  // W_in
        (const float*)d_in[2],  // b_in
        (const float*)d_in[3],  // W_out
        (const float*)d_in[4],  // b_out
        (const float*)d_in[5],  // w_f
        (const float*)d_in[6],  // w_i
        (const float*)d_in[7],  // w_u
        (const float*)d_in[8],  // w_o
        (float*)d_out);
}

// Round 2
// 248.991 us; speedup vs baseline: 1.2750x; 1.2750x over previous
//
#include <hip/hip_runtime.h>
#include <math.h>

#define B_TOT 512
#define S_LEN 256
#define D_IN  64
#define HDIM  128

typedef float v2f __attribute__((ext_vector_type(2)));

// ---- fast scalar ops (raw HW instructions; ~1-2 ulp, threshold is 1.5e-2) ----
__device__ __forceinline__ float rcp_f(float x) { return __builtin_amdgcn_rcpf(x); }
__device__ __forceinline__ float rsq_f(float x) { return __builtin_amdgcn_rsqf(x); }

__device__ __forceinline__ v2f fma2(v2f a, v2f b, v2f c) { return __builtin_elementwise_fma(a, b, c); }
__device__ __forceinline__ v2f splat2(float s) { v2f r = {s, s}; return r; }

// packed sigmoid / tanh (2 units at once; exp/rcp are scalar-only pipes)
__device__ __forceinline__ v2f sig2(v2f s) {
    v2f e = { __expf(-s.x), __expf(-s.y) };
    v2f ONE = {1.f, 1.f};
    v2f d = e + ONE;
    v2f r = { rcp_f(d.x), rcp_f(d.y) };
    return r;
}
__device__ __forceinline__ v2f tanh2(v2f s) {
    v2f t = s + s;
    v2f e = { __expf(t.x), __expf(t.y) };
    v2f ONE = {1.f, 1.f};
    v2f d = e + ONE;
    v2f r = { rcp_f(d.x), rcp_f(d.y) };
    v2f NTWO = {-2.f, -2.f};
    return fma2(r, NTWO, ONE);   // 1 - 2r
}

// ---- DPP butterfly add (VALU pipe) ----
template<int CTRL>
__device__ __forceinline__ float dpp_add(float v) {
    int t = __builtin_amdgcn_update_dpp(0, __float_as_int(v), CTRL, 0xF, 0xF, true);
    return v + __int_as_float(t);
}

// Sum over this lane's 32-lane half; result broadcast to all lanes of the half.
// xor1,2,4,8 via DPP (row-local), xor16 via ds_swizzle (stays inside each 32-group).
// No readlane (no hazard nops), no cross-32 op, no barrier.
__device__ __forceinline__ float gsum32(float v) {
    v = dpp_add<0xB1>(v);    // xor 1
    v = dpp_add<0x4E>(v);    // xor 2
    v = dpp_add<0x141>(v);   // xor 4 (row_half_mirror, valid on 4-uniform data)
    v = dpp_add<0x140>(v);   // xor 8 (row_mirror, valid on 8-uniform data)
    int s = __builtin_amdgcn_ds_swizzle(__float_as_int(v), 0x401F); // lane ^= 16 (within 32)
    return v + __int_as_float(s);
}

// 2 batch elements per wave: lanes 0-31 = batch 2*bid, lanes 32-63 = batch 2*bid+1.
// Lane (half, j) owns hidden units j, j+32, j+64, j+96 of its batch (h/c in v2f regs)
// and x features 2j, 2j+1. Reductions are 32-lane; the formerly wave-uniform
// Bloch/Pauli/z math now computes two batches at once (one per half).
__global__ void __launch_bounds__(64, 1) qlstm_kernel(
    const float* __restrict__ x,    // (B,S,D)
    const float* __restrict__ Win,  // (192,4)
    const float* __restrict__ bin,  // (4)
    const float* __restrict__ Wout, // (4,128)
    const float* __restrict__ bout, // (128)
    const float* __restrict__ wf,   // (1,3,4)
    const float* __restrict__ wi,
    const float* __restrict__ wu,
    const float* __restrict__ wo,
    float* __restrict__ out)        // outs (B,S,128) ++ hT (B,128) ++ cT (B,128)
{
    const int l  = threadIdx.x;     // 0..63
    const int j  = l & 31;          // lane within batch group
    const int bb = l >> 5;          // which batch of the pair
    const int b  = blockIdx.x * 2 + bb;

    // ---- per-lane constant weights (packed as q-pairs: A = (q0,q1), B = (q2,q3)) ----
    const float4* W4 = reinterpret_cast<const float4*>(Win);
    v2f whA[4], whB[4];             // h-part rows for units j+32k
#pragma unroll
    for (int k = 0; k < 4; ++k) {
        float4 r = W4[j + 32 * k];
        whA[k].x = r.x; whA[k].y = r.y;
        whB[k].x = r.z; whB[k].y = r.w;
    }
    float4 rx0 = W4[128 + 2 * j];
    float4 rx1 = W4[128 + 2 * j + 1];
    v2f wxA0 = {rx0.x, rx0.y}, wxB0 = {rx0.z, rx0.w};
    v2f wxA1 = {rx1.x, rx1.y}, wxB1 = {rx1.z, rx1.w};
    // b_in folded pre-reduction: each of the 32 lanes in a group adds b/32.
    const float4 bn4 = *reinterpret_cast<const float4*>(bin);
    const v2f bnA = {bn4.x * 0.03125f, bn4.y * 0.03125f};
    const v2f bnB = {bn4.z * 0.03125f, bn4.w * 0.03125f};

    // W_out packed over unit-pairs: A = units (j, j+32), B = units (j+64, j+96)
    v2f WoA[4], WoB[4];
#pragma unroll
    for (int q = 0; q < 4; ++q) {
        WoA[q].x = Wout[q * HDIM + j];      WoA[q].y = Wout[q * HDIM + j + 32];
        WoB[q].x = Wout[q * HDIM + j + 64]; WoB[q].y = Wout[q * HDIM + j + 96];
    }
    v2f boA = {bout[j],      bout[j + 32]};
    v2f boB = {bout[j + 64], bout[j + 96]};

    // ---- per-(gate,qubit) measurement coefficients u = (-sin b, cos b sin a, cos b cos a)
    // packed over q-pairs: [g][0] = (q0,q1), [g][1] = (q2,q3)
    v2f UX[4][2], UY[4][2], UZ[4][2];
    {
        const float* wg[4] = {wf, wi, wu, wo};
#pragma unroll
        for (int g = 0; g < 4; ++g) {
#pragma unroll
            for (int p = 0; p < 2; ++p) {
#pragma unroll
                for (int e = 0; e < 2; ++e) {
                    int q = 2 * p + e;
                    float a  = wg[g][q];
                    float be = wg[g][4 + q];
                    float sa = sinf(a),  ca = cosf(a);
                    float sb = sinf(be), cb = cosf(be);
                    UX[g][p][e] = -sb;
                    UY[g][p][e] = cb * sa;
                    UZ[g][p][e] = cb * ca;
                }
            }
        }
    }

    // ---- recurrent state: 4 units per lane as two v2f pairs ----
    v2f hA = {0.f, 0.f}, hB = {0.f, 0.f};
    v2f cA = {0.f, 0.f}, cB = {0.f, 0.f};

    const float* xb = x + (size_t)b * (S_LEN * D_IN) + 2 * j;
    float* ob = out + (size_t)b * (S_LEN * HDIM) + j;

    const v2f ONE = {1.f, 1.f};

    auto step = [&](v2f xf, int t) {
        // input projection partials (3 short chains, then tree-add)
        v2f pa01 = fma2(splat2(xf.x), wxA0, bnA);
        v2f pa23 = fma2(splat2(xf.x), wxB0, bnB);
        pa01 = fma2(splat2(xf.y), wxA1, pa01);
        pa23 = fma2(splat2(xf.y), wxB1, pa23);
        v2f pb01 = splat2(hA.x) * whA[0];
        v2f pb23 = splat2(hA.x) * whB[0];
        pb01 = fma2(splat2(hA.y), whA[1], pb01);
        pb23 = fma2(splat2(hA.y), whB[1], pb23);
        v2f pc01 = splat2(hB.x) * whA[2];
        v2f pc23 = splat2(hB.x) * whB[2];
        pc01 = fma2(splat2(hB.y), whA[3], pc01);
        pc23 = fma2(splat2(hB.y), whB[3], pc23);
        v2f p01 = (pa01 + pb01) + pc01;
        v2f p23 = (pa23 + pb23) + pc23;

        float y0 = gsum32(p01.x);
        float y1 = gsum32(p01.y);
        float y2 = gsum32(p23.x);
        float y3 = gsum32(p23.y);

        // Bloch vectors, packed over q-pairs (arctan's cancel analytically)
        v2f yA = {y0, y1}, yB = {y2, y3};
        v2f qA = yA * yA,  qB = yB * yB;
        v2f aA = fma2(yA, yA, ONE), aB = fma2(yB, yB, ONE);
        v2f bA = fma2(qA, qA, ONE), bB = fma2(qB, qB, ONE);
        v2f r1A = { rsq_f(aA.x), rsq_f(aA.y) };
        v2f r1B = { rsq_f(aB.x), rsq_f(aB.y) };
        v2f r2A = { rsq_f(bA.x), rsq_f(bA.y) };
        v2f r2B = { rsq_f(bB.x), rsq_f(bB.y) };
        v2f nxA = r1A * r2A, nxB = r1B * r2B;
        v2f nyA = qA * nxA,  nyB = qB * nxB;
        v2f nzA = -(yA * r1A), nzB = -(yB * r1B);
        float nx0 = nxA.x, nx1 = nxA.y, nx2 = nxB.x, nx3 = nxB.y;
        float ny0 = nyA.x, ny1 = nyA.y, ny2 = nyB.x, ny3 = nyB.y;
        float nz0 = nzA.x, nz1 = nzA.y, nz2 = nzB.x, nz3 = nzB.y;

        // Pauli-string products (CNOT-ring conjugation)
        float nz01 = nz0 * nz1;
        float nz23 = nz2 * nz3;
        v2f TXa, TXb, TYa, TYb, TZa, TZb;
        TXa.x = nx0 * nx1;  TXa.y = nx1 * nx2;
        TXb.x = nx2 * nx3;  TXb.y = TXa.x * nx3;
        TZa.x = nz1 * nz23; TZa.y = nz01;
        TZb.x = nz01 * nz2; TZb.y = nz01 * nz23;
        TYa.x = (nx0 * ny1) * nz23;  TYa.y = (nz0 * ny1) * nx2;
        TYb.x = (nz01 * ny2) * nx3;  TYb.y = -(ny0 * ny1) * (nz2 * ny3);

        // gate pre-activations: z uniform per half, s over unit-pairs (pk fma)
        v2f preA[4], preB[4];
#pragma unroll
        for (int g = 0; g < 4; ++g) {
            v2f za = fma2(UX[g][0], TXa, fma2(UY[g][0], TYa, UZ[g][0] * TZa));
            v2f zb = fma2(UX[g][1], TXb, fma2(UY[g][1], TYb, UZ[g][1] * TZb));
            v2f sA = fma2(splat2(za.x), WoA[0], boA);
            sA = fma2(splat2(za.y), WoA[1], sA);
            sA = fma2(splat2(zb.x), WoA[2], sA);
            sA = fma2(splat2(zb.y), WoA[3], sA);
            v2f sB = fma2(splat2(za.x), WoB[0], boB);
            sB = fma2(splat2(za.y), WoB[1], sB);
            sB = fma2(splat2(zb.x), WoB[2], sB);
            sB = fma2(splat2(zb.y), WoB[3], sB);
            preA[g] = sA; preB[g] = sB;
        }

        v2f fA = sig2(preA[0]),  fB = sig2(preB[0]);
        v2f iA = sig2(preA[1]),  iB = sig2(preB[1]);
        v2f gA = tanh2(preA[2]), gB = tanh2(preB[2]);
        v2f oA = sig2(preA[3]),  oB = sig2(preB[3]);
        cA = fma2(fA, cA, iA * gA);
        cB = fma2(fB, cB, iB * gB);
        hA = oA * tanh2(cA);
        hB = oB * tanh2(cB);

        // store this step's 4 units (fire-and-forget)
        float* op = ob + (size_t)t * HDIM;
        op[0]  = hA.x;
        op[32] = hA.y;
        op[64] = hB.x;
        op[96] = hB.y;
    };

    // ---- main loop: groups of 2 steps, x prefetched 2 groups (4 steps) ahead ----
    v2f xc0 = *reinterpret_cast<const v2f*>(xb + (size_t)0 * D_IN);
    v2f xc1 = *reinterpret_cast<const v2f*>(xb + (size_t)1 * D_IN);
    v2f xn0 = *reinterpret_cast<const v2f*>(xb + (size_t)2 * D_IN);
    v2f xn1 = *reinterpret_cast<const v2f*>(xb + (size_t)3 * D_IN);

    for (int grp = 0; grp < S_LEN / 2; ++grp) {
        step(xc0, 2 * grp);
        step(xc1, 2 * grp + 1);
        xc0 = xn0; xc1 = xn1;
        int t0 = 2 * grp + 4; if (t0 > S_LEN - 1) t0 = S_LEN - 1;
        int t1 = 2 * grp + 5; if (t1 > S_LEN - 1) t1 = S_LEN - 1;
        xn0 = *reinterpret_cast<const v2f*>(xb + (size_t)t0 * D_IN);
        xn1 = *reinterpret_cast<const v2f*>(xb + (size_t)t1 * D_IN);
    }

    // final h, c
    float* hT = out + (size_t)B_TOT * S_LEN * HDIM;
    float* cT = hT + (size_t)B_TOT * HDIM;
    float* hp = hT + (size_t)b * HDIM + j;
    float* cp = cT + (size_t)b * HDIM + j;
    hp[0]  = hA.x; hp[32] = hA.y; hp[64] = hB.x; hp[96] = hB.y;
    cp[0]  = cA.x; cp[32] = cA.y; cp[64] = cB.x; cp[96] = cB.y;
}

extern "C" void kernel_launch(void* const* d_in, const int* in_sizes, int n_in,
                              void* d_out, int out_size, void* d_ws, size_t ws_size,
                              hipStream_t stream) {
    qlstm_kernel<<<dim3(B_TOT / 2), dim3(64), 0, stream>>>(
        (const float*)d_in[0],  // x
        (const float*)d_in[1],  // W_in
        (const float*)d_in[2],  // b_in
        (const float*)d_in[3],  // W_out
        (const float*)d_in[4],  // b_out
        (const float*)d_in[5],  // w_f
        (const float*)d_in[6],  // w_i
        (const float*)d_in[7],  // w_u
        (const float*)d_in[8],  // w_o
        (float*)d_out);
}

// Round 3
// 239.559 us; speedup vs baseline: 1.3252x; 1.0394x over previous
//
#include <hip/hip_runtime.h>
#include <math.h>

#define B_TOT 512
#define S_LEN 256
#define D_IN  64
#define HDIM  128

typedef float v2f __attribute__((ext_vector_type(2)));

// ---- fast scalar ops (raw HW instructions; ~1-2 ulp, threshold is 1.5e-2) ----
__device__ __forceinline__ float rcp_f(float x) { return __builtin_amdgcn_rcpf(x); }
__device__ __forceinline__ float rsq_f(float x) { return __builtin_amdgcn_rsqf(x); }

__device__ __forceinline__ v2f fma2(v2f a, v2f b, v2f c) { return __builtin_elementwise_fma(a, b, c); }
__device__ __forceinline__ v2f splat2(float s) { v2f r = {s, s}; return r; }

// packed sigmoid / tanh (2 units at once)
__device__ __forceinline__ v2f sig2(v2f s) {
    v2f e = { __expf(-s.x), __expf(-s.y) };
    v2f ONE = {1.f, 1.f};
    v2f d = e + ONE;
    v2f r = { rcp_f(d.x), rcp_f(d.y) };
    return r;
}
__device__ __forceinline__ v2f tanh2(v2f s) {
    v2f t = s + s;
    v2f e = { __expf(t.x), __expf(t.y) };
    v2f ONE = {1.f, 1.f};
    v2f d = e + ONE;
    v2f r = { rcp_f(d.x), rcp_f(d.y) };
    v2f NTWO = {-2.f, -2.f};
    return fma2(r, NTWO, ONE);   // 1 - 2r
}

// ---- DPP butterfly add (VALU pipe) ----
template<int CTRL>
__device__ __forceinline__ float dpp_add(float v) {
    int t = __builtin_amdgcn_update_dpp(0, __float_as_int(v), CTRL, 0xF, 0xF, true);
    return v + __int_as_float(t);
}

// Full 64-lane sum, result broadcast to all lanes. No readlane (no hazard nops).
__device__ __forceinline__ float allsum64(float v, int idx32) {
    v = dpp_add<0xB1>(v);    // xor 1
    v = dpp_add<0x4E>(v);    // xor 2
    v = dpp_add<0x141>(v);   // xor 4 (row_half_mirror on 4-uniform data)
    v = dpp_add<0x140>(v);   // xor 8 (row_mirror on 8-uniform data)
    int s = __builtin_amdgcn_ds_swizzle(__float_as_int(v), 0x401F); // lane ^= 16
    v += __int_as_float(s);
    int t = __builtin_amdgcn_ds_bpermute(idx32, __float_as_int(v)); // lane ^= 32
    v += __int_as_float(t);
    return v;
}

// ---------------------------------------------------------------------------
// Phase 1: precompute yx[b][t][q] = b_in[q] + sum_d x[b,t,d] * Win[128+d][q].
// One wave per (b, 16-step chunk); coalesced x reads; trivially parallel.
// ---------------------------------------------------------------------------
__global__ void __launch_bounds__(64, 1) xproj_kernel(
    const float* __restrict__ x,    // (B,S,D)
    const float* __restrict__ Win,  // (192,4)
    const float* __restrict__ bin,  // (4)
    float4* __restrict__ yx)        // (B,S) float4
{
    const int l  = threadIdx.x;
    const int b  = blockIdx.x >> 4;
    const int t0 = (blockIdx.x & 15) << 4;
    const int idx32 = (l ^ 32) << 2;

    const float4 wx = reinterpret_cast<const float4*>(Win)[128 + l];
    const v2f wxa = {wx.x, wx.y}, wxb = {wx.z, wx.w};
    const float4 bn = *reinterpret_cast<const float4*>(bin);

    const float* xp = x + ((size_t)b * S_LEN + t0) * D_IN + l;
    float4* yp = yx + (size_t)b * S_LEN + t0;

#pragma unroll 4
    for (int tt = 0; tt < 16; ++tt) {
        float xv = xp[(size_t)tt * D_IN];
        v2f p01 = splat2(xv) * wxa;
        v2f p23 = splat2(xv) * wxb;
        float y0 = allsum64(p01.x, idx32);
        float y1 = allsum64(p01.y, idx32);
        float y2 = allsum64(p23.x, idx32);
        float y3 = allsum64(p23.y, idx32);
        if (l == 0)
            yp[tt] = make_float4(y0 + bn.x, y1 + bn.y, y2 + bn.z, y3 + bn.w);
    }
}

// ---------------------------------------------------------------------------
// Phase 2: serial recurrence. 1 batch per wave (512 waves, 2/CU).
// Lane l owns hidden units 2l, 2l+1 (h,c as v2f); reductions are full-wave
// butterflies; tail math packed with v_pk_fma_f32.
// PRE=1: x-projection read from yx (precomputed). PRE=0: inline (ws fallback).
// ---------------------------------------------------------------------------
template<bool PRE>
__global__ void __launch_bounds__(64, 1) qlstm_kernel(
    const float* __restrict__ x,    // (B,S,D)
    const float* __restrict__ Win,  // (192,4)
    const float* __restrict__ bin,  // (4)
    const float* __restrict__ Wout, // (4,128)
    const float* __restrict__ bout, // (128)
    const float* __restrict__ wf,   // (1,3,4)
    const float* __restrict__ wi,
    const float* __restrict__ wu,
    const float* __restrict__ wo,
    float* __restrict__ out,        // outs (B,S,128) ++ hT (B,128) ++ cT (B,128)
    const float4* __restrict__ yx)  // (B,S) precomputed x-projection (PRE only)
{
    const int l = threadIdx.x;      // 0..63
    const int b = blockIdx.x;
    const int idx32 = (l ^ 32) << 2;

    // ---- h-part W_in rows for this lane's two units (packed over q-pairs) ----
    const float4* W4 = reinterpret_cast<const float4*>(Win);
    const float4 r0 = W4[2 * l];
    const float4 r1 = W4[2 * l + 1];
    const v2f wh0a = {r0.x, r0.y}, wh0b = {r0.z, r0.w};
    const v2f wh1a = {r1.x, r1.y}, wh1b = {r1.z, r1.w};

    // x-part (fallback path only): lane owns feature l; bias folded /64
    v2f wxa = {0.f, 0.f}, wxb = {0.f, 0.f}, bna = {0.f, 0.f}, bnb = {0.f, 0.f};
    if (!PRE) {
        const float4 rx = W4[128 + l];
        wxa.x = rx.x; wxa.y = rx.y; wxb.x = rx.z; wxb.y = rx.w;
        const float4 bn = *reinterpret_cast<const float4*>(bin);
        bna.x = bn.x * 0.015625f; bna.y = bn.y * 0.015625f;
        bnb.x = bn.z * 0.015625f; bnb.y = bn.w * 0.015625f;
    }

    // W_out for units 2l, 2l+1 (packed over the unit pair)
    v2f Wo[4];
#pragma unroll
    for (int q = 0; q < 4; ++q) {
        Wo[q].x = Wout[q * HDIM + 2 * l];
        Wo[q].y = Wout[q * HDIM + 2 * l + 1];
    }
    const v2f bo = {bout[2 * l], bout[2 * l + 1]};

    // measurement coefficients, packed over q-pairs: [g][0]=(q0,q1) [g][1]=(q2,q3)
    v2f UX[4][2], UY[4][2], UZ[4][2];
    {
        const float* wg[4] = {wf, wi, wu, wo};
#pragma unroll
        for (int g = 0; g < 4; ++g) {
#pragma unroll
            for (int p = 0; p < 2; ++p) {
#pragma unroll
                for (int e = 0; e < 2; ++e) {
                    int q = 2 * p + e;
                    float a  = wg[g][q];
                    float be = wg[g][4 + q];
                    float sa = sinf(a),  ca = cosf(a);
                    float sb = sinf(be), cb = cosf(be);
                    UX[g][p][e] = -sb;
                    UY[g][p][e] = cb * sa;
                    UZ[g][p][e] = cb * ca;
                }
            }
        }
    }

    v2f h = {0.f, 0.f}, c = {0.f, 0.f};
    const v2f ONE = {1.f, 1.f};

    float* ob = out + (size_t)b * (S_LEN * HDIM) + 2 * l;

    // prefetch state (2 steps ahead)
    const float4* yxp = PRE ? (yx + (size_t)b * S_LEN) : nullptr;
    const float*  xb  = PRE ? nullptr : (x + (size_t)b * (S_LEN * D_IN) + l);
    float4 ya, yb;
    float  xa, xv_b;
    if (PRE) { ya = yxp[0]; yb = yxp[1]; }
    else     { xa = xb[0];  xv_b = xb[D_IN]; }

    for (int t = 0; t < S_LEN; ++t) {
        // ---- projection partials ----
        v2f p01, p23;
        float4 ycur;
        if (PRE) {
            ycur = ya; ya = yb;
            int tn = t + 2; if (tn > S_LEN - 1) tn = S_LEN - 1;
            yb = yxp[tn];
            p01 = fma2(splat2(h.y), wh1a, splat2(h.x) * wh0a);
            p23 = fma2(splat2(h.y), wh1b, splat2(h.x) * wh0b);
        } else {
            float xv = xa; xa = xv_b;
            int tn = t + 2; if (tn > S_LEN - 1) tn = S_LEN - 1;
            xv_b = xb[(size_t)tn * D_IN];
            p01 = fma2(splat2(h.y), wh1a, fma2(splat2(h.x), wh0a, fma2(splat2(xv), wxa, bna)));
            p23 = fma2(splat2(h.y), wh1b, fma2(splat2(h.x), wh0b, fma2(splat2(xv), wxb, bnb)));
        }

        float y0 = allsum64(p01.x, idx32);
        float y1 = allsum64(p01.y, idx32);
        float y2 = allsum64(p23.x, idx32);
        float y3 = allsum64(p23.y, idx32);

        v2f yA = {y0, y1}, yB = {y2, y3};
        if (PRE) {
            v2f xc0 = {ycur.x, ycur.y}, xc1 = {ycur.z, ycur.w};
            yA = yA + xc0;
            yB = yB + xc1;
        }

        // ---- Bloch vectors, packed over q-pairs (arctans cancel analytically) ----
        v2f qA = yA * yA,  qB = yB * yB;
        v2f aA = fma2(yA, yA, ONE), aB = fma2(yB, yB, ONE);
        v2f bA = fma2(qA, qA, ONE), bB = fma2(qB, qB, ONE);
        v2f r1A = { rsq_f(aA.x), rsq_f(aA.y) };
        v2f r1B = { rsq_f(aB.x), rsq_f(aB.y) };
        v2f r2A = { rsq_f(bA.x), rsq_f(bA.y) };
        v2f r2B = { rsq_f(bB.x), rsq_f(bB.y) };
        v2f nxA = r1A * r2A, nxB = r1B * r2B;
        v2f nyA = qA * nxA,  nyB = qB * nxB;
        v2f nzA = -(yA * r1A), nzB = -(yB * r1B);
        float nx0 = nxA.x, nx1 = nxA.y, nx2 = nxB.x, nx3 = nxB.y;
        float ny0 = nyA.x, ny1 = nyA.y, ny2 = nyB.x, ny3 = nyB.y;
        float nz0 = nzA.x, nz1 = nzA.y, nz2 = nzB.x, nz3 = nzB.y;

        // ---- Pauli-string products (CNOT-ring conjugation) ----
        float nz01 = nz0 * nz1;
        float nz23 = nz2 * nz3;
        v2f TXa, TXb, TYa, TYb, TZa, TZb;
        TXa.x = nx0 * nx1;  TXa.y = nx1 * nx2;
        TXb.x = nx2 * nx3;  TXb.y = TXa.x * nx3;
        TZa.x = nz1 * nz23; TZa.y = nz01;
        TZb.x = nz01 * nz2; TZb.y = nz01 * nz23;
        TYa.x = (nx0 * ny1) * nz23;  TYa.y = (nz0 * ny1) * nx2;
        TYb.x = (nz01 * ny2) * nx3;  TYb.y = -(ny0 * ny1) * (nz2 * ny3);

        // ---- gate pre-activations for the lane's unit pair ----
        v2f pre[4];
#pragma unroll
        for (int g = 0; g < 4; ++g) {
            v2f za = fma2(UX[g][0], TXa, fma2(UY[g][0], TYa, UZ[g][0] * TZa));
            v2f zb = fma2(UX[g][1], TXb, fma2(UY[g][1], TYb, UZ[g][1] * TZb));
            v2f s = fma2(splat2(za.x), Wo[0], bo);
            s = fma2(splat2(za.y), Wo[1], s);
            s = fma2(splat2(zb.x), Wo[2], s);
            s = fma2(splat2(zb.y), Wo[3], s);
            pre[g] = s;
        }

        v2f fg = sig2(pre[0]);
        v2f ig = sig2(pre[1]);
        v2f gg = tanh2(pre[2]);
        v2f og = sig2(pre[3]);
        c = fma2(fg, c, ig * gg);
        h = og * tanh2(c);

        // store this step's unit pair (fire-and-forget, dwordx2)
        *reinterpret_cast<v2f*>(ob + (size_t)t * HDIM) = h;
    }

    // final h, c
    float* hT = out + (size_t)B_TOT * S_LEN * HDIM;
    float* cT = hT + (size_t)B_TOT * HDIM;
    *reinterpret_cast<v2f*>(hT + (size_t)b * HDIM + 2 * l) = h;
    *reinterpret_cast<v2f*>(cT + (size_t)b * HDIM + 2 * l) = c;
}

extern "C" void kernel_launch(void* const* d_in, const int* in_sizes, int n_in,
                              void* d_out, int out_size, void* d_ws, size_t ws_size,
                              hipStream_t stream) {
    const size_t yx_bytes = (size_t)B_TOT * S_LEN * 4 * sizeof(float);  // 2 MiB
    if (d_ws != nullptr && ws_size >= yx_bytes) {
        float4* yx = (float4*)d_ws;
        xproj_kernel<<<dim3(B_TOT * 16), dim3(64), 0, stream>>>(
            (const float*)d_in[0], (const float*)d_in[1], (const float*)d_in[2], yx);
        qlstm_kernel<true><<<dim3(B_TOT), dim3(64), 0, stream>>>(
            (const float*)d_in[0], (const float*)d_in[1], (const float*)d_in[2],
            (const float*)d_in[3], (const float*)d_in[4],
            (const float*)d_in[5], (const float*)d_in[6],
            (const float*)d_in[7], (const float*)d_in[8],
            (float*)d_out, yx);
    } else {
        qlstm_kernel<false><<<dim3(B_TOT), dim3(64), 0, stream>>>(
            (const float*)d_in[0], (const float*)d_in[1], (const float*)d_in[2],
            (const float*)d_in[3], (const float*)d_in[4],
            (const float*)d_in[5], (const float*)d_in[6],
            (const float*)d_in[7], (const float*)d_in[8],
            (float*)d_out, nullptr);
    }
}

// Round 4
// 223.648 us; speedup vs baseline: 1.4195x; 1.0711x over previous
//
#include <hip/hip_runtime.h>
#include <math.h>

#define B_TOT 512
#define S_LEN 256
#define D_IN  64
#define HDIM  128

typedef float v2f __attribute__((ext_vector_type(2)));

// ---- fast scalar ops (raw HW instructions; ~1-2 ulp, threshold is 1.5e-2) ----
__device__ __forceinline__ float rcp_f(float x) { return __builtin_amdgcn_rcpf(x); }
__device__ __forceinline__ float rsq_f(float x) { return __builtin_amdgcn_rsqf(x); }

__device__ __forceinline__ v2f fma2(v2f a, v2f b, v2f c) { return __builtin_elementwise_fma(a, b, c); }
__device__ __forceinline__ v2f splat2(float s) { v2f r = {s, s}; return r; }

// packed sigmoid / tanh (2 units at once)
__device__ __forceinline__ v2f sig2(v2f s) {
    v2f e = { __expf(-s.x), __expf(-s.y) };
    v2f ONE = {1.f, 1.f};
    v2f d = e + ONE;
    v2f r = { rcp_f(d.x), rcp_f(d.y) };
    return r;
}
__device__ __forceinline__ v2f tanh2(v2f s) {
    v2f t = s + s;
    v2f e = { __expf(t.x), __expf(t.y) };
    v2f ONE = {1.f, 1.f};
    v2f d = e + ONE;
    v2f r = { rcp_f(d.x), rcp_f(d.y) };
    v2f NTWO = {-2.f, -2.f};
    return fma2(r, NTWO, ONE);   // 1 - 2r
}

// ---------------------------------------------------------------------------
// Fused 4-value 64-lane all-reduce, one asm block.
// Stages (per value): xor1, xor2, xor4(row_half_mirror on 4-uniform),
// xor8(row_mirror on 8-uniform), row_bcast:15, row_bcast:31  -> lane 63 holds
// the total; one ds_bpermute(idx=252) broadcasts it to all lanes.
// 4 values interleaved per stage => >=3 insts between DPP write and DPP read
// of the same reg (hazard-safe); s_nop 1 guards the block entry.
// Single s_waitcnt lgkmcnt(0) for the 4 bpermutes.
// ---------------------------------------------------------------------------
__device__ __forceinline__ void reduce4(float p0, float p1, float p2, float p3,
                                        float& y0, float& y1, float& y2, float& y3,
                                        int bidx) {
    asm volatile(
        "s_nop 1\n\t"
        "v_add_f32 %0, %0, %0 quad_perm:[1,0,3,2] row_mask:0xf bank_mask:0xf\n\t"
        "v_add_f32 %1, %1, %1 quad_perm:[1,0,3,2] row_mask:0xf bank_mask:0xf\n\t"
        "v_add_f32 %2, %2, %2 quad_perm:[1,0,3,2] row_mask:0xf bank_mask:0xf\n\t"
        "v_add_f32 %3, %3, %3 quad_perm:[1,0,3,2] row_mask:0xf bank_mask:0xf\n\t"
        "v_add_f32 %0, %0, %0 quad_perm:[2,3,0,1] row_mask:0xf bank_mask:0xf\n\t"
        "v_add_f32 %1, %1, %1 quad_perm:[2,3,0,1] row_mask:0xf bank_mask:0xf\n\t"
        "v_add_f32 %2, %2, %2 quad_perm:[2,3,0,1] row_mask:0xf bank_mask:0xf\n\t"
        "v_add_f32 %3, %3, %3 quad_perm:[2,3,0,1] row_mask:0xf bank_mask:0xf\n\t"
        "v_add_f32 %0, %0, %0 row_half_mirror row_mask:0xf bank_mask:0xf\n\t"
        "v_add_f32 %1, %1, %1 row_half_mirror row_mask:0xf bank_mask:0xf\n\t"
        "v_add_f32 %2, %2, %2 row_half_mirror row_mask:0xf bank_mask:0xf\n\t"
        "v_add_f32 %3, %3, %3 row_half_mirror row_mask:0xf bank_mask:0xf\n\t"
        "v_add_f32 %0, %0, %0 row_mirror row_mask:0xf bank_mask:0xf\n\t"
        "v_add_f32 %1, %1, %1 row_mirror row_mask:0xf bank_mask:0xf\n\t"
        "v_add_f32 %2, %2, %2 row_mirror row_mask:0xf bank_mask:0xf\n\t"
        "v_add_f32 %3, %3, %3 row_mirror row_mask:0xf bank_mask:0xf\n\t"
        "v_add_f32 %0, %0, %0 row_bcast:15 row_mask:0xf bank_mask:0xf bound_ctrl:0\n\t"
        "v_add_f32 %1, %1, %1 row_bcast:15 row_mask:0xf bank_mask:0xf bound_ctrl:0\n\t"
        "v_add_f32 %2, %2, %2 row_bcast:15 row_mask:0xf bank_mask:0xf bound_ctrl:0\n\t"
        "v_add_f32 %3, %3, %3 row_bcast:15 row_mask:0xf bank_mask:0xf bound_ctrl:0\n\t"
        "v_add_f32 %0, %0, %0 row_bcast:31 row_mask:0xf bank_mask:0xf bound_ctrl:0\n\t"
        "v_add_f32 %1, %1, %1 row_bcast:31 row_mask:0xf bank_mask:0xf bound_ctrl:0\n\t"
        "v_add_f32 %2, %2, %2 row_bcast:31 row_mask:0xf bank_mask:0xf bound_ctrl:0\n\t"
        "v_add_f32 %3, %3, %3 row_bcast:31 row_mask:0xf bank_mask:0xf bound_ctrl:0\n\t"
        "ds_bpermute_b32 %4, %8, %0\n\t"
        "ds_bpermute_b32 %5, %8, %1\n\t"
        "ds_bpermute_b32 %6, %8, %2\n\t"
        "ds_bpermute_b32 %7, %8, %3\n\t"
        "s_waitcnt lgkmcnt(0)"
        : "+v"(p0), "+v"(p1), "+v"(p2), "+v"(p3),
          "=&v"(y0), "=&v"(y1), "=&v"(y2), "=&v"(y3)
        : "v"(bidx));
}

// ---------------------------------------------------------------------------
// Phase 1: precompute yx[b][t][q] = b_in[q] + sum_d x[b,t,d] * Win[128+d][q].
// ---------------------------------------------------------------------------
__global__ void __launch_bounds__(64, 1) xproj_kernel(
    const float* __restrict__ x,    // (B,S,D)
    const float* __restrict__ Win,  // (192,4)
    const float* __restrict__ bin,  // (4)
    float4* __restrict__ yx)        // (B,S) float4
{
    const int l  = threadIdx.x;
    const int b  = blockIdx.x >> 4;
    const int t0 = (blockIdx.x & 15) << 4;
    const int bidx = 252;           // bpermute byte index of lane 63

    const float4 wx = reinterpret_cast<const float4*>(Win)[128 + l];
    const float4 bn = *reinterpret_cast<const float4*>(bin);

    const float* xp = x + ((size_t)b * S_LEN + t0) * D_IN + l;
    float4* yp = yx + (size_t)b * S_LEN + t0;

#pragma unroll 4
    for (int tt = 0; tt < 16; ++tt) {
        float xv = xp[(size_t)tt * D_IN];
        float y0, y1, y2, y3;
        reduce4(xv * wx.x, xv * wx.y, xv * wx.z, xv * wx.w, y0, y1, y2, y3, bidx);
        if (l == 0)
            yp[tt] = make_float4(y0 + bn.x, y1 + bn.y, y2 + bn.z, y3 + bn.w);
    }
}

// ---------------------------------------------------------------------------
// Phase 2: serial recurrence. 1 batch per wave (512 waves, 2/CU).
// Lane l owns hidden units 2l, 2l+1. yx row staged in LDS once (no SMEM in
// loop -> the reduction's lgkmcnt(0) never drains a long-latency prefetch).
// ---------------------------------------------------------------------------
template<bool PRE>
__global__ void __launch_bounds__(64, 1) qlstm_kernel(
    const float* __restrict__ x,    // (B,S,D)
    const float* __restrict__ Win,  // (192,4)
    const float* __restrict__ bin,  // (4)
    const float* __restrict__ Wout, // (4,128)
    const float* __restrict__ bout, // (128)
    const float* __restrict__ wf,   // (1,3,4)
    const float* __restrict__ wi,
    const float* __restrict__ wu,
    const float* __restrict__ wo,
    float* __restrict__ out,        // outs (B,S,128) ++ hT (B,128) ++ cT (B,128)
    const float4* __restrict__ yx)  // (B,S) precomputed x-projection (PRE only)
{
    const int l = threadIdx.x;      // 0..63
    const int b = blockIdx.x;
    const int bidx = 252;           // bpermute byte index of lane 63

    __shared__ float4 yxl[S_LEN + 2];   // staged x-projection (+2 pad for prefetch)

    // ---- h-part W_in rows for this lane's two units (packed over q-pairs) ----
    const float4* W4 = reinterpret_cast<const float4*>(Win);
    const float4 r0 = W4[2 * l];
    const float4 r1 = W4[2 * l + 1];
    const v2f wh0a = {r0.x, r0.y}, wh0b = {r0.z, r0.w};
    const v2f wh1a = {r1.x, r1.y}, wh1b = {r1.z, r1.w};

    // x-part (fallback path only): lane owns feature l; bias folded /64
    v2f wxa = {0.f, 0.f}, wxb = {0.f, 0.f}, bna = {0.f, 0.f}, bnb = {0.f, 0.f};
    if (!PRE) {
        const float4 rx = W4[128 + l];
        wxa.x = rx.x; wxa.y = rx.y; wxb.x = rx.z; wxb.y = rx.w;
        const float4 bn = *reinterpret_cast<const float4*>(bin);
        bna.x = bn.x * 0.015625f; bna.y = bn.y * 0.015625f;
        bnb.x = bn.z * 0.015625f; bnb.y = bn.w * 0.015625f;
    } else {
        // stage this batch's yx row into LDS (single wave: no barrier needed)
        const float4* yxg = yx + (size_t)b * S_LEN;
#pragma unroll
        for (int k = 0; k < 4; ++k)
            yxl[(k << 6) + l] = yxg[(k << 6) + l];
    }

    // W_out for units 2l, 2l+1 (packed over the unit pair)
    v2f Wo[4];
#pragma unroll
    for (int q = 0; q < 4; ++q) {
        Wo[q].x = Wout[q * HDIM + 2 * l];
        Wo[q].y = Wout[q * HDIM + 2 * l + 1];
    }
    const v2f bo = {bout[2 * l], bout[2 * l + 1]};

    // measurement coefficients, packed over q-pairs: [g][0]=(q0,q1) [g][1]=(q2,q3)
    v2f UX[4][2], UY[4][2], UZ[4][2];
    {
        const float* wg[4] = {wf, wi, wu, wo};
#pragma unroll
        for (int g = 0; g < 4; ++g) {
#pragma unroll
            for (int p = 0; p < 2; ++p) {
#pragma unroll
                for (int e = 0; e < 2; ++e) {
                    int q = 2 * p + e;
                    float a  = wg[g][q];
                    float be = wg[g][4 + q];
                    float sa = sinf(a),  ca = cosf(a);
                    float sb = sinf(be), cb = cosf(be);
                    UX[g][p][e] = -sb;
                    UY[g][p][e] = cb * sa;
                    UZ[g][p][e] = cb * ca;
                }
            }
        }
    }

    v2f h = {0.f, 0.f}, c = {0.f, 0.f};
    const v2f ONE = {1.f, 1.f};

    float* ob = out + (size_t)b * (S_LEN * HDIM) + 2 * l;

    // prefetch state
    float4 ycur, yn;
    const float* xb = PRE ? nullptr : (x + (size_t)b * (S_LEN * D_IN) + l);
    float xa = 0.f, xv_b = 0.f;
    if (PRE) { ycur = yxl[0]; yn = yxl[1]; }
    else     { xa = xb[0];    xv_b = xb[D_IN]; }

    for (int t = 0; t < S_LEN; ++t) {
        // ---- projection partials (h-part; x-part precomputed on PRE path) ----
        v2f p01, p23;
        if (PRE) {
            p01 = fma2(splat2(h.y), wh1a, splat2(h.x) * wh0a);
            p23 = fma2(splat2(h.y), wh1b, splat2(h.x) * wh0b);
        } else {
            float xv = xa; xa = xv_b;
            int tn = t + 2; if (tn > S_LEN - 1) tn = S_LEN - 1;
            xv_b = xb[(size_t)tn * D_IN];
            p01 = fma2(splat2(h.y), wh1a, fma2(splat2(h.x), wh0a, fma2(splat2(xv), wxa, bna)));
            p23 = fma2(splat2(h.y), wh1b, fma2(splat2(h.x), wh0b, fma2(splat2(xv), wxb, bnb)));
        }

        float y0, y1, y2, y3;
        reduce4(p01.x, p01.y, p23.x, p23.y, y0, y1, y2, y3, bidx);

        v2f yA = {y0, y1}, yB = {y2, y3};
        if (PRE) {
            v2f xc0 = {ycur.x, ycur.y}, xc1 = {ycur.z, ycur.w};
            yA = yA + xc0;
            yB = yB + xc1;
        }

        // issue next-next yx LDS read (2-deep; waited at the earliest by the
        // NEXT step's lgkmcnt(0), ~a full step after issue)
        float4 yread2;
        if (PRE) yread2 = yxl[t + 2];

        // ---- Bloch vectors, packed over q-pairs (arctans cancel analytically) ----
        v2f qA = yA * yA,  qB = yB * yB;
        v2f aA = fma2(yA, yA, ONE), aB = fma2(yB, yB, ONE);
        v2f bA = fma2(qA, qA, ONE), bB = fma2(qB, qB, ONE);
        v2f r1A = { rsq_f(aA.x), rsq_f(aA.y) };
        v2f r1B = { rsq_f(aB.x), rsq_f(aB.y) };
        v2f r2A = { rsq_f(bA.x), rsq_f(bA.y) };
        v2f r2B = { rsq_f(bB.x), rsq_f(bB.y) };
        v2f nxA = r1A * r2A, nxB = r1B * r2B;
        v2f nyA = qA * nxA,  nyB = qB * nxB;
        v2f nzA = -(yA * r1A), nzB = -(yB * r1B);
        float nx0 = nxA.x, nx1 = nxA.y, nx2 = nxB.x, nx3 = nxB.y;
        float ny0 = nyA.x, ny1 = nyA.y, ny2 = nyB.x, ny3 = nyB.y;
        float nz0 = nzA.x, nz1 = nzA.y, nz2 = nzB.x, nz3 = nzB.y;

        // ---- Pauli-string products (CNOT-ring conjugation) ----
        float nz01 = nz0 * nz1;
        float nz23 = nz2 * nz3;
        v2f TXa, TXb, TYa, TYb, TZa, TZb;
        TXa.x = nx0 * nx1;  TXa.y = nx1 * nx2;
        TXb.x = nx2 * nx3;  TXb.y = TXa.x * nx3;
        TZa.x = nz1 * nz23; TZa.y = nz01;
        TZb.x = nz01 * nz2; TZb.y = nz01 * nz23;
        TYa.x = (nx0 * ny1) * nz23;  TYa.y = (nz0 * ny1) * nx2;
        TYb.x = (nz01 * ny2) * nx3;  TYb.y = -(ny0 * ny1) * (nz2 * ny3);

        // ---- gate pre-activations for the lane's unit pair ----
        v2f pre[4];
#pragma unroll
        for (int g = 0; g < 4; ++g) {
            v2f za = fma2(UX[g][0], TXa, fma2(UY[g][0], TYa, UZ[g][0] * TZa));
            v2f zb = fma2(UX[g][1], TXb, fma2(UY[g][1], TYb, UZ[g][1] * TZb));
            v2f s = fma2(splat2(za.x), Wo[0], bo);
            s = fma2(splat2(za.y), Wo[1], s);
            s = fma2(splat2(zb.x), Wo[2], s);
            s = fma2(splat2(zb.y), Wo[3], s);
            pre[g] = s;
        }

        v2f fg = sig2(pre[0]);
        v2f ig = sig2(pre[1]);
        v2f gg = tanh2(pre[2]);
        v2f og = sig2(pre[3]);
        c = fma2(fg, c, ig * gg);
        h = og * tanh2(c);

        // rotate yx prefetch
        if (PRE) { ycur = yn; yn = yread2; }

        // store this step's unit pair (fire-and-forget, dwordx2)
        *reinterpret_cast<v2f*>(ob + (size_t)t * HDIM) = h;
    }

    // final h, c
    float* hT = out + (size_t)B_TOT * S_LEN * HDIM;
    float* cT = hT + (size_t)B_TOT * HDIM;
    *reinterpret_cast<v2f*>(hT + (size_t)b * HDIM + 2 * l) = h;
    *reinterpret_cast<v2f*>(cT + (size_t)b * HDIM + 2 * l) = c;
}

extern "C" void kernel_launch(void* const* d_in, const int* in_sizes, int n_in,
                              void* d_out, int out_size, void* d_ws, size_t ws_size,
                              hipStream_t stream) {
    const size_t yx_bytes = (size_t)B_TOT * S_LEN * 4 * sizeof(float);  // 2 MiB
    if (d_ws != nullptr && ws_size >= yx_bytes) {
        float4* yx = (float4*)d_ws;
        xproj_kernel<<<dim3(B_TOT * 16), dim3(64), 0, stream>>>(
            (const float*)d_in[0], (const float*)d_in[1], (const float*)d_in[2], yx);
        qlstm_kernel<true><<<dim3(B_TOT), dim3(64), 0, stream>>>(
            (const float*)d_in[0], (const float*)d_in[1], (const float*)d_in[2],
            (const float*)d_in[3], (const float*)d_in[4],
            (const float*)d_in[5], (const float*)d_in[6],
            (const float*)d_in[7], (const float*)d_in[8],
            (float*)d_out, yx);
    } else {
        qlstm_kernel<false><<<dim3(B_TOT), dim3(64), 0, stream>>>(
            (const float*)d_in[0], (const float*)d_in[1], (const float*)d_in[2],
            (const float*)d_in[3], (const float*)d_in[4],
            (const float*)d_in[5], (const float*)d_in[6],
            (const float*)d_in[7], (const float*)d_in[8],
            (float*)d_out, nullptr);
    }
}

// Round 5
// 214.644 us; speedup vs baseline: 1.4791x; 1.0420x over previous
//
#include <hip/hip_runtime.h>
#include <math.h>

#define B_TOT 512
#define S_LEN 256
#define D_IN  64
#define HDIM  128

typedef float v2f __attribute__((ext_vector_type(2)));

// ---- fast scalar ops (raw HW instructions; ~1-2 ulp, threshold is 1.5e-2) ----
__device__ __forceinline__ float rcp_f(float x) { return __builtin_amdgcn_rcpf(x); }
__device__ __forceinline__ float rsq_f(float x) { return __builtin_amdgcn_rsqf(x); }

__device__ __forceinline__ v2f fma2(v2f a, v2f b, v2f c) { return __builtin_elementwise_fma(a, b, c); }
__device__ __forceinline__ v2f splat2(float s) { v2f r = {s, s}; return r; }

// packed sigmoid / tanh (2 units at once)
__device__ __forceinline__ v2f sig2(v2f s) {
    v2f e = { __expf(-s.x), __expf(-s.y) };
    v2f ONE = {1.f, 1.f};
    v2f d = e + ONE;
    v2f r = { rcp_f(d.x), rcp_f(d.y) };
    return r;
}
__device__ __forceinline__ v2f tanh2(v2f s) {
    v2f t = s + s;
    v2f e = { __expf(t.x), __expf(t.y) };
    v2f ONE = {1.f, 1.f};
    v2f d = e + ONE;
    v2f r = { rcp_f(d.x), rcp_f(d.y) };
    v2f NTWO = {-2.f, -2.f};
    return fma2(r, NTWO, ONE);   // 1 - 2r
}

// ---------------------------------------------------------------------------
// Fused 4-value 64-lane all-reduce, one asm block, NO LDS.
// Stages (per value): xor1, xor2, xor4(row_half_mirror on 4-uniform),
// xor8(row_mirror on 8-uniform), row_bcast:15, row_bcast:31 -> lanes 48-63
// hold the full total (proven: round-4 kernel read lane 63 via bpermute and
// passed). v_readlane lane 63 -> SGPR: no LDS round-trip, no lgkmcnt wait.
// 4-chain interleave gives >=3 insts between DPP write and dependent read;
// s_nop 1 guards block entry and the readlane hazard window.
// ---------------------------------------------------------------------------
__device__ __forceinline__ void reduce4(float p0, float p1, float p2, float p3,
                                        float& y0, float& y1, float& y2, float& y3) {
    asm volatile(
        "s_nop 1\n\t"
        "v_add_f32 %0, %0, %0 quad_perm:[1,0,3,2] row_mask:0xf bank_mask:0xf\n\t"
        "v_add_f32 %1, %1, %1 quad_perm:[1,0,3,2] row_mask:0xf bank_mask:0xf\n\t"
        "v_add_f32 %2, %2, %2 quad_perm:[1,0,3,2] row_mask:0xf bank_mask:0xf\n\t"
        "v_add_f32 %3, %3, %3 quad_perm:[1,0,3,2] row_mask:0xf bank_mask:0xf\n\t"
        "v_add_f32 %0, %0, %0 quad_perm:[2,3,0,1] row_mask:0xf bank_mask:0xf\n\t"
        "v_add_f32 %1, %1, %1 quad_perm:[2,3,0,1] row_mask:0xf bank_mask:0xf\n\t"
        "v_add_f32 %2, %2, %2 quad_perm:[2,3,0,1] row_mask:0xf bank_mask:0xf\n\t"
        "v_add_f32 %3, %3, %3 quad_perm:[2,3,0,1] row_mask:0xf bank_mask:0xf\n\t"
        "v_add_f32 %0, %0, %0 row_half_mirror row_mask:0xf bank_mask:0xf\n\t"
        "v_add_f32 %1, %1, %1 row_half_mirror row_mask:0xf bank_mask:0xf\n\t"
        "v_add_f32 %2, %2, %2 row_half_mirror row_mask:0xf bank_mask:0xf\n\t"
        "v_add_f32 %3, %3, %3 row_half_mirror row_mask:0xf bank_mask:0xf\n\t"
        "v_add_f32 %0, %0, %0 row_mirror row_mask:0xf bank_mask:0xf\n\t"
        "v_add_f32 %1, %1, %1 row_mirror row_mask:0xf bank_mask:0xf\n\t"
        "v_add_f32 %2, %2, %2 row_mirror row_mask:0xf bank_mask:0xf\n\t"
        "v_add_f32 %3, %3, %3 row_mirror row_mask:0xf bank_mask:0xf\n\t"
        "v_add_f32 %0, %0, %0 row_bcast:15 row_mask:0xf bank_mask:0xf bound_ctrl:0\n\t"
        "v_add_f32 %1, %1, %1 row_bcast:15 row_mask:0xf bank_mask:0xf bound_ctrl:0\n\t"
        "v_add_f32 %2, %2, %2 row_bcast:15 row_mask:0xf bank_mask:0xf bound_ctrl:0\n\t"
        "v_add_f32 %3, %3, %3 row_bcast:15 row_mask:0xf bank_mask:0xf bound_ctrl:0\n\t"
        "v_add_f32 %0, %0, %0 row_bcast:31 row_mask:0xf bank_mask:0xf bound_ctrl:0\n\t"
        "v_add_f32 %1, %1, %1 row_bcast:31 row_mask:0xf bank_mask:0xf bound_ctrl:0\n\t"
        "v_add_f32 %2, %2, %2 row_bcast:31 row_mask:0xf bank_mask:0xf bound_ctrl:0\n\t"
        "v_add_f32 %3, %3, %3 row_bcast:31 row_mask:0xf bank_mask:0xf bound_ctrl:0\n\t"
        "s_nop 1\n\t"
        "v_readlane_b32 %4, %0, 63\n\t"
        "v_readlane_b32 %5, %1, 63\n\t"
        "v_readlane_b32 %6, %2, 63\n\t"
        "v_readlane_b32 %7, %3, 63"
        : "+v"(p0), "+v"(p1), "+v"(p2), "+v"(p3),
          "=&s"(y0), "=&s"(y1), "=&s"(y2), "=&s"(y3));
}

// ---------------------------------------------------------------------------
// Phase 1: precompute yx[b][t][q] = b_in[q] + sum_d x[b,t,d] * Win[128+d][q].
// ---------------------------------------------------------------------------
__global__ void __launch_bounds__(64, 1) xproj_kernel(
    const float* __restrict__ x,    // (B,S,D)
    const float* __restrict__ Win,  // (192,4)
    const float* __restrict__ bin,  // (4)
    float4* __restrict__ yx)        // (B,S) float4
{
    const int l  = threadIdx.x;
    const int b  = blockIdx.x >> 4;
    const int t0 = (blockIdx.x & 15) << 4;

    const float4 wx = reinterpret_cast<const float4*>(Win)[128 + l];
    const float4 bn = *reinterpret_cast<const float4*>(bin);

    const float* xp = x + ((size_t)b * S_LEN + t0) * D_IN + l;
    float4* yp = yx + (size_t)b * S_LEN + t0;

#pragma unroll 4
    for (int tt = 0; tt < 16; ++tt) {
        float xv = xp[(size_t)tt * D_IN];
        float y0, y1, y2, y3;
        reduce4(xv * wx.x, xv * wx.y, xv * wx.z, xv * wx.w, y0, y1, y2, y3);
        if (l == 0)
            yp[tt] = make_float4(y0 + bn.x, y1 + bn.y, y2 + bn.z, y3 + bn.w);
    }
}

// ---------------------------------------------------------------------------
// Phase 2: serial recurrence. 1 batch per wave (512 waves, 2/CU).
// Lane l owns hidden units 2l, 2l+1. yx row staged in LDS once; with the
// readlane reduction the yx ds_read prefetch is the ONLY lgkm op in the loop
// (2-deep prefetch -> its wait is always satisfied when reached).
// ---------------------------------------------------------------------------
template<bool PRE>
__global__ void __launch_bounds__(64, 1) qlstm_kernel(
    const float* __restrict__ x,    // (B,S,D)
    const float* __restrict__ Win,  // (192,4)
    const float* __restrict__ bin,  // (4)
    const float* __restrict__ Wout, // (4,128)
    const float* __restrict__ bout, // (128)
    const float* __restrict__ wf,   // (1,3,4)
    const float* __restrict__ wi,
    const float* __restrict__ wu,
    const float* __restrict__ wo,
    float* __restrict__ out,        // outs (B,S,128) ++ hT (B,128) ++ cT (B,128)
    const float4* __restrict__ yx)  // (B,S) precomputed x-projection (PRE only)
{
    const int l = threadIdx.x;      // 0..63
    const int b = blockIdx.x;

    __shared__ float4 yxl[S_LEN + 2];   // staged x-projection (+2 pad for prefetch)

    // ---- h-part W_in rows for this lane's two units (packed over q-pairs) ----
    const float4* W4 = reinterpret_cast<const float4*>(Win);
    const float4 r0 = W4[2 * l];
    const float4 r1 = W4[2 * l + 1];
    const v2f wh0a = {r0.x, r0.y}, wh0b = {r0.z, r0.w};
    const v2f wh1a = {r1.x, r1.y}, wh1b = {r1.z, r1.w};

    // x-part (fallback path only): lane owns feature l; bias folded /64
    v2f wxa = {0.f, 0.f}, wxb = {0.f, 0.f}, bna = {0.f, 0.f}, bnb = {0.f, 0.f};
    if (!PRE) {
        const float4 rx = W4[128 + l];
        wxa.x = rx.x; wxa.y = rx.y; wxb.x = rx.z; wxb.y = rx.w;
        const float4 bn = *reinterpret_cast<const float4*>(bin);
        bna.x = bn.x * 0.015625f; bna.y = bn.y * 0.015625f;
        bnb.x = bn.z * 0.015625f; bnb.y = bn.w * 0.015625f;
    } else {
        // stage this batch's yx row into LDS (single wave: no barrier needed)
        const float4* yxg = yx + (size_t)b * S_LEN;
#pragma unroll
        for (int k = 0; k < 4; ++k)
            yxl[(k << 6) + l] = yxg[(k << 6) + l];
    }

    // W_out for units 2l, 2l+1 (packed over the unit pair)
    v2f Wo[4];
#pragma unroll
    for (int q = 0; q < 4; ++q) {
        Wo[q].x = Wout[q * HDIM + 2 * l];
        Wo[q].y = Wout[q * HDIM + 2 * l + 1];
    }
    const v2f bo = {bout[2 * l], bout[2 * l + 1]};

    // measurement coefficients, packed over q-pairs: [g][0]=(q0,q1) [g][1]=(q2,q3)
    v2f UX[4][2], UY[4][2], UZ[4][2];
    {
        const float* wg[4] = {wf, wi, wu, wo};
#pragma unroll
        for (int g = 0; g < 4; ++g) {
#pragma unroll
            for (int p = 0; p < 2; ++p) {
#pragma unroll
                for (int e = 0; e < 2; ++e) {
                    int q = 2 * p + e;
                    float a  = wg[g][q];
                    float be = wg[g][4 + q];
                    float sa = sinf(a),  ca = cosf(a);
                    float sb = sinf(be), cb = cosf(be);
                    UX[g][p][e] = -sb;
                    UY[g][p][e] = cb * sa;
                    UZ[g][p][e] = cb * ca;
                }
            }
        }
    }

    v2f h = {0.f, 0.f}, c = {0.f, 0.f};
    const v2f ONE = {1.f, 1.f};

    float* ob = out + (size_t)b * (S_LEN * HDIM) + 2 * l;

    // prefetch state
    float4 ycur, yn;
    const float* xb = PRE ? nullptr : (x + (size_t)b * (S_LEN * D_IN) + l);
    float xa = 0.f, xv_b = 0.f;
    if (PRE) { ycur = yxl[0]; yn = yxl[1]; }
    else     { xa = xb[0];    xv_b = xb[D_IN]; }

    for (int t = 0; t < S_LEN; ++t) {
        // ---- projection partials (h-part; x-part precomputed on PRE path) ----
        v2f p01, p23;
        if (PRE) {
            p01 = fma2(splat2(h.y), wh1a, splat2(h.x) * wh0a);
            p23 = fma2(splat2(h.y), wh1b, splat2(h.x) * wh0b);
        } else {
            float xv = xa; xa = xv_b;
            int tn = t + 2; if (tn > S_LEN - 1) tn = S_LEN - 1;
            xv_b = xb[(size_t)tn * D_IN];
            p01 = fma2(splat2(h.y), wh1a, fma2(splat2(h.x), wh0a, fma2(splat2(xv), wxa, bna)));
            p23 = fma2(splat2(h.y), wh1b, fma2(splat2(h.x), wh0b, fma2(splat2(xv), wxb, bnb)));
        }

        float y0, y1, y2, y3;
        reduce4(p01.x, p01.y, p23.x, p23.y, y0, y1, y2, y3);

        // y sums arrive in SGPRs; combine with yx (VALU reads SGPR directly)
        v2f yA, yB;
        if (PRE) {
            yA.x = y0 + ycur.x;  yA.y = y1 + ycur.y;
            yB.x = y2 + ycur.z;  yB.y = y3 + ycur.w;
        } else {
            yA.x = y0; yA.y = y1; yB.x = y2; yB.y = y3;
        }

        // issue next-next yx LDS read (2-deep; only lgkm op in the loop)
        float4 yread2;
        if (PRE) yread2 = yxl[t + 2];

        // ---- Bloch vectors, packed over q-pairs (arctans cancel analytically) ----
        v2f qA = yA * yA,  qB = yB * yB;
        v2f aA = fma2(yA, yA, ONE), aB = fma2(yB, yB, ONE);
        v2f bA = fma2(qA, qA, ONE), bB = fma2(qB, qB, ONE);
        v2f r1A = { rsq_f(aA.x), rsq_f(aA.y) };
        v2f r1B = { rsq_f(aB.x), rsq_f(aB.y) };
        v2f r2A = { rsq_f(bA.x), rsq_f(bA.y) };
        v2f r2B = { rsq_f(bB.x), rsq_f(bB.y) };
        v2f nxA = r1A * r2A, nxB = r1B * r2B;
        v2f nyA = qA * nxA,  nyB = qB * nxB;
        v2f nzA = -(yA * r1A), nzB = -(yB * r1B);
        float nx0 = nxA.x, nx1 = nxA.y, nx2 = nxB.x, nx3 = nxB.y;
        float ny0 = nyA.x, ny1 = nyA.y, ny2 = nyB.x, ny3 = nyB.y;
        float nz0 = nzA.x, nz1 = nzA.y, nz2 = nzB.x, nz3 = nzB.y;

        // ---- Pauli-string products (CNOT-ring conjugation) ----
        float nz01 = nz0 * nz1;
        float nz23 = nz2 * nz3;
        v2f TXa, TXb, TYa, TYb, TZa, TZb;
        TXa.x = nx0 * nx1;  TXa.y = nx1 * nx2;
        TXb.x = nx2 * nx3;  TXb.y = TXa.x * nx3;
        TZa.x = nz1 * nz23; TZa.y = nz01;
        TZb.x = nz01 * nz2; TZb.y = nz01 * nz23;
        TYa.x = (nx0 * ny1) * nz23;  TYa.y = (nz0 * ny1) * nx2;
        TYb.x = (nz01 * ny2) * nx3;  TYb.y = -(ny0 * ny1) * (nz2 * ny3);

        // ---- gate pre-activations for the lane's unit pair ----
        v2f pre[4];
#pragma unroll
        for (int g = 0; g < 4; ++g) {
            v2f za = fma2(UX[g][0], TXa, fma2(UY[g][0], TYa, UZ[g][0] * TZa));
            v2f zb = fma2(UX[g][1], TXb, fma2(UY[g][1], TYb, UZ[g][1] * TZb));
            v2f s = fma2(splat2(za.x), Wo[0], bo);
            s = fma2(splat2(za.y), Wo[1], s);
            s = fma2(splat2(zb.x), Wo[2], s);
            s = fma2(splat2(zb.y), Wo[3], s);
            pre[g] = s;
        }

        v2f fg = sig2(pre[0]);
        v2f ig = sig2(pre[1]);
        v2f gg = tanh2(pre[2]);
        v2f og = sig2(pre[3]);
        c = fma2(fg, c, ig * gg);
        h = og * tanh2(c);

        // rotate yx prefetch
        if (PRE) { ycur = yn; yn = yread2; }

        // store this step's unit pair (fire-and-forget, dwordx2)
        *reinterpret_cast<v2f*>(ob + (size_t)t * HDIM) = h;
    }

    // final h, c
    float* hT = out + (size_t)B_TOT * S_LEN * HDIM;
    float* cT = hT + (size_t)B_TOT * HDIM;
    *reinterpret_cast<v2f*>(hT + (size_t)b * HDIM + 2 * l) = h;
    *reinterpret_cast<v2f*>(cT + (size_t)b * HDIM + 2 * l) = c;
}

extern "C" void kernel_launch(void* const* d_in, const int* in_sizes, int n_in,
                              void* d_out, int out_size, void* d_ws, size_t ws_size,
                              hipStream_t stream) {
    const size_t yx_bytes = (size_t)B_TOT * S_LEN * 4 * sizeof(float);  // 2 MiB
    if (d_ws != nullptr && ws_size >= yx_bytes) {
        float4* yx = (float4*)d_ws;
        xproj_kernel<<<dim3(B_TOT * 16), dim3(64), 0, stream>>>(
            (const float*)d_in[0], (const float*)d_in[1], (const float*)d_in[2], yx);
        qlstm_kernel<true><<<dim3(B_TOT), dim3(64), 0, stream>>>(
            (const float*)d_in[0], (const float*)d_in[1], (const float*)d_in[2],
            (const float*)d_in[3], (const float*)d_in[4],
            (const float*)d_in[5], (const float*)d_in[6],
            (const float*)d_in[7], (const float*)d_in[8],
            (float*)d_out, yx);
    } else {
        qlstm_kernel<false><<<dim3(B_TOT), dim3(64), 0, stream>>>(
            (const float*)d_in[0], (const float*)d_in[1], (const float*)d_in[2],
            (const float*)d_in[3], (const float*)d_in[4],
            (const float*)d_in[5], (const float*)d_in[6],
            (const float*)d_in[7], (const float*)d_in[8],
            (float*)d_out, nullptr);
    }
}